// Round 1
// baseline (196.786 us; speedup 1.0000x reference)
//
#include <hip/hip_runtime.h>
#include <hip/hip_bf16.h>
#include <math.h>
#include <stdint.h>

#define B_    2
#define T_    2048
#define C_    1024
#define H_    16
#define D_    64
#define R_    4
#define DSTD  60
#define F_    3072
#define BT_   (B_ * T_)

#define LOG2E 1.44269504088896340736f

typedef __bf16 bf16x8 __attribute__((ext_vector_type(8)));
typedef __bf16 bf16x4 __attribute__((ext_vector_type(4)));
typedef float  f32x4  __attribute__((ext_vector_type(4)));
typedef float  f32x16 __attribute__((ext_vector_type(16)));

// per-row XOR swizzle of 8-element column blocks (unpadded 64-col rows).
__device__ __forceinline__ int swz(int row, int blk) {
    return blk ^ ((row >> 1) & 7);
}

// async global->LDS, 16B per lane; dest = linear base + lane*16.
__device__ __forceinline__ void gload_lds16(const void* g, void* l) {
    __builtin_amdgcn_global_load_lds(
        (const __attribute__((address_space(1))) uint32_t*)g,
        (__attribute__((address_space(3))) uint32_t*)l, 16, 0, 0);
}

// pack two f32 -> one u32 of 2 bf16 (compiler emits v_cvt_pk; RNE like casts)
__device__ __forceinline__ uint32_t pack2(float lo, float hi) {
    union { __bf16 h[2]; uint32_t u; } t;
    t.h[0] = (__bf16)lo; t.h[1] = (__bf16)hi;
    return t.u;
}

// lanes<32 of b swap with lanes>=32 of a: a' = [a_lo|b_lo], b' = [a_hi|b_hi]
__device__ __forceinline__ void plswap(uint32_t& a, uint32_t& b) {
    asm volatile("v_permlane32_swap_b32 %0, %1" : "+v"(a), "+v"(b));
}

// ---------------------------------------------------------------------------
// fused fp32 -> bf16 cast of x, W_attn, W_proj (one launch)
// ---------------------------------------------------------------------------
__global__ __launch_bounds__(256) void cast3_kernel(
    const float* __restrict__ a, int na4,
    const float* __restrict__ b, int nb4,
    const float* __restrict__ c, int nc4,
    __bf16* __restrict__ oa, __bf16* __restrict__ ob, __bf16* __restrict__ oc)
{
    int i = blockIdx.x * 256 + threadIdx.x;
    const float* s; __bf16* d; int j = i;
    if (j < na4) { s = a; d = oa; }
    else {
        j -= na4;
        if (j < nb4) { s = b; d = ob; }
        else {
            j -= nb4;
            if (j >= nc4) return;
            s = c; d = oc;
        }
    }
    float4 v = ((const float4*)s)[j];
    bf16x4 o;
    o[0] = (__bf16)v.x; o[1] = (__bf16)v.y;
    o[2] = (__bf16)v.z; o[3] = (__bf16)v.w;
    ((bf16x4*)d)[j] = o;
}

// ---------------------------------------------------------------------------
// m97-style bf16 MFMA GEMM: out = A(M,K) @ B(N,K)^T. 128x128 tile, 256 thr.
// GEMM1 epilogue: scale q/k (Q gets 1/sqrt(D) AND log2(e) folded in),
// scatter bf16 into (B,H,T,D) Q/K/V.
// ---------------------------------------------------------------------------
__global__ __launch_bounds__(256) void gemm_qkv_kernel(
    const __bf16* __restrict__ A,    // x   (BT, C) bf16
    const __bf16* __restrict__ Bw,   // Wa  (F,  C) bf16
    const float* __restrict__ w_std, const float* __restrict__ w_rec,
    const float* __restrict__ skip_std, const float* __restrict__ skip_low,
    __bf16* __restrict__ Q, __bf16* __restrict__ K, __bf16* __restrict__ V)
{
    __shared__ __bf16 As[128 * 32];
    __shared__ __bf16 Bs[128 * 32];

    const int tid  = threadIdx.x;
    const int row0 = blockIdx.x * 128;
    const int col0 = blockIdx.y * 128;

    const int w    = tid >> 6;
    const int lane = tid & 63;
    const int quad = lane >> 4;
    const int lt   = lane & 15;
    const int wm   = w >> 1;
    const int wn   = w & 1;

    const int lrow = tid >> 2;
    const int lcol = (tid & 3) * 8;

    f32x4 acc[4][4];
#pragma unroll
    for (int i = 0; i < 4; ++i)
#pragma unroll
        for (int j = 0; j < 4; ++j)
#pragma unroll
            for (int r = 0; r < 4; ++r) acc[i][j][r] = 0.f;

    for (int kt = 0; kt < C_ / 32; ++kt) {
        const int k0 = kt * 32;
        __syncthreads();
#pragma unroll
        for (int rr = 0; rr < 2; ++rr) {
            gload_lds16(A  + (size_t)(row0 + rr * 64 + lrow) * C_ + k0 + lcol,
                        As + rr * 2048 + tid * 8);
            gload_lds16(Bw + (size_t)(col0 + rr * 64 + lrow) * C_ + k0 + lcol,
                        Bs + rr * 2048 + tid * 8);
        }
        __syncthreads();

        bf16x8 af[4], bf[4];
#pragma unroll
        for (int i = 0; i < 4; ++i)
            af[i] = *(const bf16x8*)&As[(wm * 64 + i * 16 + lt) * 32 + quad * 8];
#pragma unroll
        for (int j = 0; j < 4; ++j)
            bf[j] = *(const bf16x8*)&Bs[(wn * 64 + j * 16 + lt) * 32 + quad * 8];
#pragma unroll
        for (int i = 0; i < 4; ++i)
#pragma unroll
            for (int j = 0; j < 4; ++j)
                acc[i][j] = __builtin_amdgcn_mfma_f32_16x16x32_bf16(af[i], bf[j], acc[i][j], 0, 0, 0);
    }

    const int colbase = col0 + wn * 64;
    const int which   = colbase >> 10;
    const int h       = (colbase & (C_ - 1)) >> 6;

    const float ss = 1.f / (1.f + __expf(-skip_std[0]));
    const float sl = 1.f / (1.f + __expf(-skip_low[0]));
    const float gs = sqrtf(fmaxf(w_std[h] * ss, 1e-8f));
    const float gr = sqrtf(fmaxf(w_rec[h] * sl, 1e-8f));

    __bf16* dstM = (which == 0) ? Q : (which == 1) ? K : V;

#pragma unroll
    for (int i = 0; i < 4; ++i) {
#pragma unroll
        for (int r = 0; r < 4; ++r) {
            const int row = row0 + wm * 64 + i * 16 + quad * 4 + r;
            const int b = row >> 11;
            const int t = row & (T_ - 1);
            __bf16* dp = dstM + (((size_t)b * H_ + h) * T_ + t) * D_;
#pragma unroll
            for (int j = 0; j < 4; ++j) {
                const int d = j * 16 + lt;
                float val = acc[i][j][r];
                if (which == 0)      val *= ((d < DSTD) ? gs : gr) * (0.125f * LOG2E);
                else if (which == 1) val *= (d < DSTD) ? gs : gr;
                dp[d] = (__bf16)val;
            }
        }
    }
}

// ---------------------------------------------------------------------------
// GEMM2: out = Y(BT,C) @ Wp(C,C)^T, fp32 out.
// ---------------------------------------------------------------------------
__global__ __launch_bounds__(256) void gemm_out_kernel(
    const __bf16* __restrict__ A,
    const __bf16* __restrict__ Bw,
    float* __restrict__ out)
{
    __shared__ __bf16 As[128 * 32];
    __shared__ __bf16 Bs[128 * 32];

    const int tid  = threadIdx.x;
    const int row0 = blockIdx.x * 128;
    const int col0 = blockIdx.y * 128;

    const int w    = tid >> 6;
    const int lane = tid & 63;
    const int quad = lane >> 4;
    const int lt   = lane & 15;
    const int wm   = w >> 1;
    const int wn   = w & 1;

    const int lrow = tid >> 2;
    const int lcol = (tid & 3) * 8;

    f32x4 acc[4][4];
#pragma unroll
    for (int i = 0; i < 4; ++i)
#pragma unroll
        for (int j = 0; j < 4; ++j)
#pragma unroll
            for (int r = 0; r < 4; ++r) acc[i][j][r] = 0.f;

    for (int kt = 0; kt < C_ / 32; ++kt) {
        const int k0 = kt * 32;
        __syncthreads();
#pragma unroll
        for (int rr = 0; rr < 2; ++rr) {
            gload_lds16(A  + (size_t)(row0 + rr * 64 + lrow) * C_ + k0 + lcol,
                        As + rr * 2048 + tid * 8);
            gload_lds16(Bw + (size_t)(col0 + rr * 64 + lrow) * C_ + k0 + lcol,
                        Bs + rr * 2048 + tid * 8);
        }
        __syncthreads();

        bf16x8 af[4], bf[4];
#pragma unroll
        for (int i = 0; i < 4; ++i)
            af[i] = *(const bf16x8*)&As[(wm * 64 + i * 16 + lt) * 32 + quad * 8];
#pragma unroll
        for (int j = 0; j < 4; ++j)
            bf[j] = *(const bf16x8*)&Bs[(wn * 64 + j * 16 + lt) * 32 + quad * 8];
#pragma unroll
        for (int i = 0; i < 4; ++i)
#pragma unroll
            for (int j = 0; j < 4; ++j)
                acc[i][j] = __builtin_amdgcn_mfma_f32_16x16x32_bf16(af[i], bf[j], acc[i][j], 0, 0, 0);
    }

#pragma unroll
    for (int i = 0; i < 4; ++i)
#pragma unroll
        for (int r = 0; r < 4; ++r) {
            const int row = row0 + wm * 64 + i * 16 + quad * 4 + r;
            float* op = out + (size_t)row * C_ + col0 + wn * 64 + lt;
#pragma unroll
            for (int j = 0; j < 4; ++j)
                op[j * 16] = acc[i][j][r];
        }
}

// ---------------------------------------------------------------------------
// MFMA flash attention, 32x32x16 restructure:
//   * 128 threads = 2 waves, each wave owns 32 queries (block = 64 q, grid
//     and qt load-balance permutation unchanged).
//   * S^T = K.Q^T via mfma_f32_32x32x16_bf16: lane's 16 S values are 16 keys
//     of its OWN query column (col=lane&31) -> softmax is lane-local.
//   * P never touches LDS: pack f32 pairs to bf16 words (compiler cvt_pk)
//     and exchange key-halves with v_permlane32_swap_b32 -> PV A-frags in
//     registers (T12). Ps buffer deleted (LDS 40KB -> 32KB).
//   * K staged by global_load_lds DMA with swizzle-compensated global column
//     permutation; V reg-transposed into Vt[d][key] (4 keys x 8 d / thread).
//   * Denominator via ones-MFMA: its C row mapping equals oacc's, so the
//     epilogue 1/l lookup is register-local.
// ---------------------------------------------------------------------------
__global__ __launch_bounds__(128) void attn_kernel(
    const __bf16* __restrict__ Q, const __bf16* __restrict__ K,
    const __bf16* __restrict__ V, const float* __restrict__ rwr_alpha,
    __bf16* __restrict__ Y)   // (B,T,C) bf16
{
    __shared__ __align__(16) __bf16 Ks[2][64][64];
    __shared__ __align__(16) __bf16 Vt[2][64][64];   // Vt[d][key], swizzled

    const int tid = threadIdx.x;
    const int bh  = blockIdx.x & 31;               // b*H + h
    const int g   = blockIdx.x >> 5;               // 0..31
    // balanced 4-way permutation: qt(g)+qt(g+8)+qt(g+16)+qt(g+24) == 62
    const int qt  = (g < 8) ? (31 - g) : (g < 16) ? (g - 8)
                  : (g < 24) ? (39 - g) : (g - 16);
    const int h   = bh & (H_ - 1);
    const int b   = bh >> 4;

    const __bf16* Qb = Q + (((size_t)b * H_ + h) * T_) * D_;
    const __bf16* Kb = K + (((size_t)b * H_ + h) * T_) * D_;
    const __bf16* Vb = V + (((size_t)b * H_ + h) * T_) * D_;

    const int w    = tid >> 6;        // wave 0/1 -> q rows [32w, 32w+31]
    const int lane = tid & 63;
    const int lq   = lane & 31;       // q column (S^T) / d column (PV)
    const int hi   = lane >> 5;

    // K DMA addressing: 4 calls x (128 lanes x 16B = 16 rows). Global column
    // block swizzle-inverted so linear DMA dest equals the swizzled layout.
    const int krb = tid >> 3;         // 0..15
    const int kcb = tid & 7;

    // V staging: 4 adjacent keys x 8 d per thread (register transpose)
    const int kp = (tid >> 3) * 4;    // key base (0..60)
    const int dc = (tid & 7) * 8;     // d col base
    const int vblk = kp >> 3, voff = kp & 7;

    // ---- Q B-frags direct from global (Q carries log2e/sqrt(D)) ----
    const __bf16* qrow = Qb + (size_t)(qt * 64 + w * 32 + lq) * D_;
    bf16x8 qf[4];
#pragma unroll
    for (int kk = 0; kk < 4; ++kk)
        qf[kk] = *(const bf16x8*)(qrow + kk * 16 + hi * 8);

    // all-ones B-frag for the denominator MFMA
    bf16x8 ones;
#pragma unroll
    for (int u = 0; u < 8; ++u) ones[u] = (__bf16)1.0f;

    // ---- stage tile 0 into buffer 0 ----
#pragma unroll
    for (int cc = 0; cc < 4; ++cc) {
        const int kr = cc * 16 + krb;
        const int kc = kcb ^ ((kr >> 1) & 7);
        gload_lds16(Kb + (size_t)kr * 64 + kc * 8,
                    &Ks[0][0][0] + cc * 1024 + tid * 8);
    }
    {
        const __bf16* vs = Vb + (size_t)kp * 64 + dc;
        bf16x8 v0 = *(const bf16x8*)(vs);
        bf16x8 v1 = *(const bf16x8*)(vs + 64);
        bf16x8 v2 = *(const bf16x8*)(vs + 128);
        bf16x8 v3 = *(const bf16x8*)(vs + 192);
#pragma unroll
        for (int u = 0; u < 8; ++u) {
            const int row = dc + u;
            bf16x4 t; t[0] = v0[u]; t[1] = v1[u]; t[2] = v2[u]; t[3] = v3[u];
            *(bf16x4*)&Vt[0][row][swz(row, vblk) * 8 + voff] = t;
        }
    }
    __syncthreads();

    f32x16 oacc[2], lacc;
#pragma unroll
    for (int r = 0; r < 16; ++r) { oacc[0][r] = 0.f; oacc[1][r] = 0.f; lacc[r] = 0.f; }

    for (int kt = 0; kt <= qt; ++kt) {
        const int cur = kt & 1;
        const int nxt = cur ^ 1;
        const bool pre = (kt < qt);

        // ---- prefetch next tile: K via DMA into nxt buffer, V into regs ----
        bf16x8 v0, v1, v2, v3;
        if (pre) {
            const size_t toff = (size_t)(kt + 1) * 4096;
#pragma unroll
            for (int cc = 0; cc < 4; ++cc) {
                const int kr = cc * 16 + krb;
                const int kc = kcb ^ ((kr >> 1) & 7);
                gload_lds16(Kb + toff + (size_t)kr * 64 + kc * 8,
                            &Ks[nxt][0][0] + cc * 1024 + tid * 8);
            }
            const __bf16* vs = Vb + toff + (size_t)kp * 64 + dc;
            v0 = *(const bf16x8*)(vs);
            v1 = *(const bf16x8*)(vs + 64);
            v2 = *(const bf16x8*)(vs + 128);
            v3 = *(const bf16x8*)(vs + 192);
        }

        // ---- two 32-key blocks ----
#pragma unroll
        for (int kb = 0; kb < 2; ++kb) {
            // S^T = K.Q^T (log2 domain): rows = keys, cols = queries
            f32x16 sacc;
#pragma unroll
            for (int r = 0; r < 16; ++r) sacc[r] = 0.f;
            const int arow = kb * 32 + lq;
#pragma unroll
            for (int kk = 0; kk < 4; ++kk) {
                bf16x8 ak = *(const bf16x8*)&Ks[cur][arow][swz(arow, kk * 2 + hi) * 8];
                sacc = __builtin_amdgcn_mfma_f32_32x32x16_bf16(ak, qf[kk], sacc, 0, 0, 0);
            }

            // causal mask on the diagonal tile: key_local > q_local
            if (kt == qt) {
                const int ql = w * 32 + lq;
#pragma unroll
                for (int r = 0; r < 16; ++r) {
                    const int key = kb * 32 + (r & 3) + ((r >> 2) << 3) + hi * 4;
                    if (key > ql) sacc[r] = -1e30f;
                }
            }

            // exp2 + in-register P->bf16 A-frags via pack + permlane32_swap
#pragma unroll
            for (int c = 0; c < 2; ++c) {
                const int rb = 8 * c;
                float p0 = __builtin_amdgcn_exp2f(sacc[rb + 0]);
                float p1 = __builtin_amdgcn_exp2f(sacc[rb + 1]);
                float p2 = __builtin_amdgcn_exp2f(sacc[rb + 2]);
                float p3 = __builtin_amdgcn_exp2f(sacc[rb + 3]);
                float p4 = __builtin_amdgcn_exp2f(sacc[rb + 4]);
                float p5 = __builtin_amdgcn_exp2f(sacc[rb + 5]);
                float p6 = __builtin_amdgcn_exp2f(sacc[rb + 6]);
                float p7 = __builtin_amdgcn_exp2f(sacc[rb + 7]);

                uint32_t w0 = pack2(p0, p1);
                uint32_t w2 = pack2(p4, p5);
                plswap(w0, w2);          // w0 = frag word j0, w2 = j2
                uint32_t w1 = pack2(p2, p3);
                uint32_t w3 = pack2(p6, p7);
                plswap(w1, w3);          // w1 = j1, w3 = j3

                union { uint32_t u[4]; bf16x8 v; } pf;
                pf.u[0] = w0; pf.u[1] = w1; pf.u[2] = w2; pf.u[3] = w3;

                // denominator: rowsum(P) per q, row-mapping identical to oacc
                lacc = __builtin_amdgcn_mfma_f32_32x32x16_bf16(pf.v, ones, lacc, 0, 0, 0);

                const int kk2 = kb * 2 + c;
#pragma unroll
                for (int db = 0; db < 2; ++db) {
                    const int drow = db * 32 + lq;
                    bf16x8 bv = *(const bf16x8*)&Vt[cur][drow][swz(drow, kk2 * 2 + hi) * 8];
                    oacc[db] = __builtin_amdgcn_mfma_f32_32x32x16_bf16(pf.v, bv, oacc[db], 0, 0, 0);
                }
            }
        }

        // ---- overflow guard (cold; never taken for these inputs) ----
        {
            float lm = lacc[0];
#pragma unroll
            for (int r = 1; r < 16; ++r) lm = fmaxf(lm, lacc[r]);
            if (__ballot(lm > 1.0e12f)) {
                const float sc = 1.0f / 4294967296.0f;   // 2^-32
#pragma unroll
                for (int r = 0; r < 16; ++r) {
                    lacc[r] *= sc; oacc[0][r] *= sc; oacc[1][r] *= sc;
                }
            }
        }

        // ---- write prefetched V into the other buffer; ONE barrier ----
        // (barrier's vmcnt drain also covers the K DMA into nxt)
        if (pre) {
#pragma unroll
            for (int u = 0; u < 8; ++u) {
                const int row = dc + u;
                bf16x4 t; t[0] = v0[u]; t[1] = v1[u]; t[2] = v2[u]; t[3] = v3[u];
                *(bf16x4*)&Vt[nxt][row][swz(row, vblk) * 8 + voff] = t;
            }
        }
        __syncthreads();
    }

    // ---- epilogue: lacc rows == oacc rows; O is normal layout ----
    const float a = fminf(fmaxf(rwr_alpha[h], 0.f), 0.5f);
#pragma unroll
    for (int r = 0; r < 16; ++r) {
        const float inv = 1.f / lacc[r];
        const int qg = qt * 64 + w * 32 + (r & 3) + ((r >> 2) << 3) + hi * 4;
        const __bf16* vp = Vb + (size_t)qg * D_;
        __bf16* yp = Y + ((size_t)(b * T_ + qg)) * C_ + h * D_;
#pragma unroll
        for (int db = 0; db < 2; ++db) {
            const int d = db * 32 + lq;
            yp[d] = (__bf16)((1.f - a) * oacc[db][r] * inv + a * (float)vp[d]);
        }
    }
}

extern "C" void kernel_launch(void* const* d_in, const int* in_sizes, int n_in,
                              void* d_out, int out_size, void* d_ws, size_t ws_size,
                              hipStream_t stream) {
    const float* x        = (const float*)d_in[0];
    const float* W_attn   = (const float*)d_in[1];
    const float* W_proj   = (const float*)d_in[2];
    const float* w_std    = (const float*)d_in[3];
    const float* w_rec    = (const float*)d_in[4];
    const float* skip_std = (const float*)d_in[5];
    const float* skip_low = (const float*)d_in[6];
    const float* rwr      = (const float*)d_in[7];
    float* out = (float*)d_out;

    const size_t nX  = (size_t)BT_ * C_;
    const size_t nWa = (size_t)F_ * C_;
    const size_t nWp = (size_t)C_ * C_;
    const size_t per = (size_t)B_ * H_ * T_ * D_;

    __bf16* xb  = (__bf16*)d_ws;
    __bf16* Wab = xb  + nX;
    __bf16* Wpb = Wab + nWa;
    __bf16* Qb  = Wpb + nWp;
    __bf16* Kb  = Qb  + per;
    __bf16* Vb  = Kb  + per;
    __bf16* Yb  = Vb  + per;

    const int na4 = nX / 4, nb4 = nWa / 4, nc4 = nWp / 4;
    cast3_kernel<<<dim3((na4 + nb4 + nc4 + 255) / 256), 256, 0, stream>>>(
        x, na4, W_attn, nb4, W_proj, nc4, xb, Wab, Wpb);

    gemm_qkv_kernel<<<dim3(BT_ / 128, F_ / 128), 256, 0, stream>>>(
        xb, Wab, w_std, w_rec, skip_std, skip_low, Qb, Kb, Vb);
    attn_kernel<<<dim3(32 * (T_ / 64)), 128, 0, stream>>>(Qb, Kb, Vb, rwr, Yb);
    gemm_out_kernel<<<dim3(BT_ / 128, C_ / 128), 256, 0, stream>>>(Yb, Wpb, out);
}